// Round 3
// baseline (10551.692 us; speedup 1.0000x reference)
//
#include <hip/hip_runtime.h>
#include <hip/hip_bf16.h>

#define S 2048
#define NEGV -10000.0f

typedef unsigned long long ull;

__device__ __forceinline__ float fsig(float x) {
  return 1.0f / (1.0f + __expf(-x));
}
__device__ __forceinline__ float ftanh(float x) {
  float a = fabsf(x);
  float e = __expf(-2.0f * a);
  float r = (1.0f - e) / (1.0f + e);
  return copysignf(r, x);
}

// ---------------- init: seed h0 with stamp 1, invalidate other slot ----------------
__global__ void init_h_k(const float* __restrict__ h0, ull* __restrict__ hbuf) {
  int dir = blockIdx.x;          // 0,1
  int u = threadIdx.x;           // 0..511
  ull pk = (1ULL << 32) | (ull)__float_as_uint(h0[dir * 512 + u]);
  __hip_atomic_store(&hbuf[dir * 1024 + u], pk, __ATOMIC_RELAXED, __HIP_MEMORY_SCOPE_AGENT);
  __hip_atomic_store(&hbuf[dir * 1024 + 512 + u], 0ULL, __ATOMIC_RELAXED, __HIP_MEMORY_SCOPE_AGENT);
}

// ---------------- xg GEMM: xg[m][n] = emb[sent[m]] . Wrow(n) + bias(n) ----------------
__global__ __launch_bounds__(256) void gemm_xg_k(
    const int* __restrict__ sent, const float* __restrict__ emb,
    const float* __restrict__ Wih_f, const float* __restrict__ Wih_b,
    const float* __restrict__ bih_f, const float* __restrict__ bhh_f,
    const float* __restrict__ bih_b, const float* __restrict__ bhh_b,
    float* __restrict__ xg)
{
  __shared__ __align__(16) float Asm[64 * 36];   // [64][36] pad
  __shared__ __align__(16) float Bsm[32 * 68];   // [32][68] pad, B[kk][n]
  __shared__ int sidx[64];

  const int bx = blockIdx.x;     // N tile 0..63
  const int by = blockIdx.y;     // M tile 0..31
  const int t = threadIdx.x;
  const int n0 = bx * 64, m0 = by * 64;

  const float* W = (n0 < 2048) ? (Wih_f + (size_t)n0 * 1024)
                               : (Wih_b + (size_t)(n0 - 2048) * 1024);
  if (t < 64) sidx[t] = sent[m0 + t];
  __syncthreads();

  const int tm = t >> 4, tn = t & 15;
  const int lr = t >> 2, lkq = t & 3;   // loader: row, k-quarter (8 floats)
  float acc[4][4] = {};

  for (int k0 = 0; k0 < 1024; k0 += 32) {
    const float* ap = emb + (size_t)sidx[lr] * 1024 + k0 + lkq * 8;
    float4 a0 = *(const float4*)ap;
    float4 a1 = *(const float4*)(ap + 4);
    const float* bp = W + (size_t)lr * 1024 + k0 + lkq * 8;
    float4 b0 = *(const float4*)bp;
    float4 b1 = *(const float4*)(bp + 4);
    __syncthreads();   // prior compute done before LDS overwrite
    *(float4*)&Asm[lr * 36 + lkq * 8]     = a0;
    *(float4*)&Asm[lr * 36 + lkq * 8 + 4] = a1;
    {
      const float* bb0 = (const float*)&b0;
      const float* bb1 = (const float*)&b1;
      #pragma unroll
      for (int j = 0; j < 4; ++j) Bsm[(lkq * 8 + j) * 68 + lr] = bb0[j];
      #pragma unroll
      for (int j = 0; j < 4; ++j) Bsm[(lkq * 8 + 4 + j) * 68 + lr] = bb1[j];
    }
    __syncthreads();
    #pragma unroll
    for (int kk = 0; kk < 32; ++kk) {
      float a0_ = Asm[(tm * 4 + 0) * 36 + kk];
      float a1_ = Asm[(tm * 4 + 1) * 36 + kk];
      float a2_ = Asm[(tm * 4 + 2) * 36 + kk];
      float a3_ = Asm[(tm * 4 + 3) * 36 + kk];
      float4 bv = *(const float4*)&Bsm[kk * 68 + tn * 4];
      acc[0][0] = fmaf(a0_, bv.x, acc[0][0]); acc[0][1] = fmaf(a0_, bv.y, acc[0][1]);
      acc[0][2] = fmaf(a0_, bv.z, acc[0][2]); acc[0][3] = fmaf(a0_, bv.w, acc[0][3]);
      acc[1][0] = fmaf(a1_, bv.x, acc[1][0]); acc[1][1] = fmaf(a1_, bv.y, acc[1][1]);
      acc[1][2] = fmaf(a1_, bv.z, acc[1][2]); acc[1][3] = fmaf(a1_, bv.w, acc[1][3]);
      acc[2][0] = fmaf(a2_, bv.x, acc[2][0]); acc[2][1] = fmaf(a2_, bv.y, acc[2][1]);
      acc[2][2] = fmaf(a2_, bv.z, acc[2][2]); acc[2][3] = fmaf(a2_, bv.w, acc[2][3]);
      acc[3][0] = fmaf(a3_, bv.x, acc[3][0]); acc[3][1] = fmaf(a3_, bv.y, acc[3][1]);
      acc[3][2] = fmaf(a3_, bv.z, acc[3][2]); acc[3][3] = fmaf(a3_, bv.w, acc[3][3]);
    }
  }

  const float* bi = (n0 < 2048) ? bih_f : bih_b;
  const float* bh = (n0 < 2048) ? bhh_f : bhh_b;
  const int nb = (n0 < 2048) ? n0 : (n0 - 2048);
  #pragma unroll
  for (int i = 0; i < 4; ++i) {
    int m = m0 + tm * 4 + i;
    #pragma unroll
    for (int j = 0; j < 4; ++j) {
      int nn = tn * 4 + j;
      float bias = bi[nb + nn] + bh[nb + nn];
      xg[(size_t)m * 4096 + n0 + nn] = acc[i][j] + bias;
    }
  }
}

// ---------------- persistent bidirectional LSTM recurrence (barrier-free waves) ----
// grid = 128 WGs x 256 thr = 512 waves. dir = wg&1, wid = wg>>1.
// Wave wv (0..3) of a WG owns units wid*8 + wv*2 + {0,1}. Each wave is fully
// independent: polls ALL 512 stamped (stamp<<32|f32) entries itself (8 per lane),
// stages h in a wave-private padded LDS region (no __syncthreads in the loop),
// computes its 8 gate-rows, and 2 lanes publish results. Slot-parity + stamp
// fusion keeps the protocol race-free at wave granularity.
__global__ __launch_bounds__(256, 1) void lstm_rec_k(
    const float* __restrict__ Whh_f, const float* __restrict__ Whh_b,
    const float* __restrict__ c0,
    const float* __restrict__ xg,      // [S][4096]
    ull* __restrict__ hbuf,            // [2 dir][2 slot][512]
    float* __restrict__ hs_cat)        // [S][1024]
{
  const int w = blockIdx.x;
  const int dir = w & 1;
  const int wid = w >> 1;              // 0..63
  const int t = threadIdx.x;
  const int wv = t >> 6;               // wave 0..3
  const int l  = t & 63;               // lane
  const int rr = l >> 3;               // row-in-wave 0..7
  const int seg = l & 7;               // 0..7
  const int g  = rr & 3;               // gate 0..3 (i,f,g,o)
  const int ul = rr >> 2;              // local unit 0..1
  const int unit = wid * 8 + wv * 2 + ul;   // 0..511
  const int grow = g * 512 + unit;          // global Whh row

  const float* Whh = dir ? Whh_b : Whh_f;

  float wreg[64];
  {
    const float* src = Whh + (size_t)grow * 512 + seg * 64;
    #pragma unroll
    for (int j = 0; j < 16; ++j) {
      float4 v = *(const float4*)(src + j * 4);
      wreg[4 * j + 0] = v.x; wreg[4 * j + 1] = v.y;
      wreg[4 * j + 2] = v.z; wreg[4 * j + 3] = v.w;
    }
  }

  // wave-private h staging: 8 chunks * 68-float stride (bank-spread, 16B aligned)
  __shared__ __align__(16) float h_lds[4][544];
  float* hw = h_lds[wv];

  ull* hb = hbuf + dir * 1024;

  float c_reg = c0[dir * 512 + unit];  // meaningful on g==0 lanes

  // poll set: lane l covers units l*8 .. l*8+7  (all in LDS chunk l>>3)
  const int myu = l * 8;
  float* ldst = &hw[(l >> 3) * 68 + (l & 7) * 8];

  // xg 2-step software pipeline: value for step k was loaded during step k-1
  float xg_cur = 0.0f, xg_next = 0.0f;
  if (seg == 0) {
    int rowk = dir ? (S - 1) : 0;
    xg_cur = xg[(size_t)rowk * 4096 + dir * 2048 + grow];
  }

  for (int k = 0; k < S; ++k) {
    // issue next step's xg load early (latency hides under this step's poll)
    if (seg == 0 && k + 1 < S) {
      int rowk = dir ? (S - 2 - k) : (k + 1);
      xg_next = xg[(size_t)rowk * 4096 + dir * 2048 + grow];
    }
    // poll h_k: stamp k+1 in slot k&1
    ull v[8];
    {
      ull* src = hb + (k & 1) * 512 + myu;
      const unsigned want = (unsigned)(k + 1);
      #pragma unroll
      for (int j = 0; j < 8; ++j)
        v[j] = __hip_atomic_load(&src[j], __ATOMIC_RELAXED, __HIP_MEMORY_SCOPE_AGENT);
      for (;;) {
        bool ok = true;
        #pragma unroll
        for (int j = 0; j < 8; ++j) ok &= ((unsigned)(v[j] >> 32) == want);
        if (ok) break;
        #pragma unroll
        for (int j = 0; j < 8; ++j)
          if ((unsigned)(v[j] >> 32) != want)
            v[j] = __hip_atomic_load(&src[j], __ATOMIC_RELAXED, __HIP_MEMORY_SCOPE_AGENT);
      }
    }
    // stage to wave-private LDS (same-wave ordering via lgkmcnt; no barrier)
    {
      float4 f0, f1;
      f0.x = __uint_as_float((unsigned)v[0]); f0.y = __uint_as_float((unsigned)v[1]);
      f0.z = __uint_as_float((unsigned)v[2]); f0.w = __uint_as_float((unsigned)v[3]);
      f1.x = __uint_as_float((unsigned)v[4]); f1.y = __uint_as_float((unsigned)v[5]);
      f1.z = __uint_as_float((unsigned)v[6]); f1.w = __uint_as_float((unsigned)v[7]);
      ((float4*)ldst)[0] = f0;
      ((float4*)ldst)[1] = f1;
    }
    // partial dot: this thread's 64-wide segment of row `grow`
    float p0 = 0.f, p1 = 0.f, p2 = 0.f, p3 = 0.f;
    const float4* h4 = (const float4*)(hw + seg * 68);
    #pragma unroll
    for (int j = 0; j < 16; ++j) {
      float4 hv = h4[j];
      p0 = fmaf(wreg[4 * j + 0], hv.x, p0);
      p1 = fmaf(wreg[4 * j + 1], hv.y, p1);
      p2 = fmaf(wreg[4 * j + 2], hv.z, p2);
      p3 = fmaf(wreg[4 * j + 3], hv.w, p3);
    }
    float p = (p0 + p1) + (p2 + p3) + xg_cur;   // xg_cur nonzero only on seg==0
    // butterfly within 8-lane segment group -> all 8 lanes hold the row sum
    p += __shfl_xor(p, 1);
    p += __shfl_xor(p, 2);
    p += __shfl_xor(p, 4);
    // gather the 4 gates of this unit (rows 8 lanes apart) in-register
    float gb_ = __shfl_xor(p, 8);     // gate g^1
    float gc_ = __shfl_xor(p, 16);    // gate g^2
    float gd_ = __shfl_xor(gb_, 16);  // gate g^3
    if (g == 0) {
      float iv = fsig(p), fv = fsig(gb_), ov = fsig(gd_);
      float gv = ftanh(gc_);
      c_reg = fv * c_reg + iv * gv;
      float hv = ov * ftanh(c_reg);
      if (seg == 0) {
        int orig = dir ? (S - 1 - k) : k;
        hs_cat[(size_t)orig * 1024 + dir * 512 + unit] = hv;
        ull pk = ((ull)(unsigned)(k + 2) << 32) | (ull)__float_as_uint(hv);
        __hip_atomic_store(&hb[((k + 1) & 1) * 512 + unit], pk,
                           __ATOMIC_RELAXED, __HIP_MEMORY_SCOPE_AGENT);
      }
    }
    xg_cur = xg_next;
  }
}

// ---------------- feats[t][j] = hs_cat[t] . Wout[j] + bout[j] ----------------
__global__ __launch_bounds__(64) void feats_k(
    const float* __restrict__ hs_cat, const float* __restrict__ Wout,
    const float* __restrict__ bout, float* __restrict__ feats)
{
  int tpos = blockIdx.x;
  int l = threadIdx.x;
  int j = l & 15, q = l >> 4;
  const float* h = hs_cat + (size_t)tpos * 1024 + q * 256;
  const float* wv = Wout + (size_t)j * 1024 + q * 256;
  float s = 0.f;
  #pragma unroll 8
  for (int i = 0; i < 256; i += 4) {
    float4 hv = *(const float4*)(h + i);
    float4 ww = *(const float4*)(wv + i);
    s = fmaf(hv.x, ww.x, s); s = fmaf(hv.y, ww.y, s);
    s = fmaf(hv.z, ww.z, s); s = fmaf(hv.w, ww.w, s);
  }
  s += __shfl_xor(s, 16);
  s += __shfl_xor(s, 32);
  if (q == 0) feats[tpos * 16 + j] = s + bout[j];
}

// ---------------- Viterbi: single wave, LDS-chunked feats, 4-bit backpointers ----------------
__global__ __launch_bounds__(64, 1) void viterbi_k(
    const float* __restrict__ feats, const float* __restrict__ trans,
    float* __restrict__ out)
{
  __shared__ __align__(16) float fch[2][256 * 16];  // 2 x 16KB double-buffer
  __shared__ unsigned char bp4[S * 8];              // 16KB packed nibbles
  __shared__ float v_lds[2][16];                    // double-buffered by step parity

  const int l = threadIdx.x;
  const int next = l & 15, q = l >> 4;

  float tr0 = trans[next * 16 + q * 4 + 0];
  float tr1 = trans[next * 16 + q * 4 + 1];
  float tr2 = trans[next * 16 + q * 4 + 2];
  float tr3 = trans[next * 16 + q * 4 + 3];

  if (l < 16) v_lds[0][l] = (l == 0) ? 0.0f : NEGV;   // START = 0

  const float4* f4 = (const float4*)feats;
  float4 buf[16];
  #pragma unroll
  for (int i = 0; i < 16; ++i) buf[i] = f4[i * 64 + l];
  #pragma unroll
  for (int i = 0; i < 16; ++i) ((float4*)fch[0])[i * 64 + l] = buf[i];
  __syncthreads();

  for (int c = 0; c < 8; ++c) {
    if (c < 7) {
      #pragma unroll
      for (int i = 0; i < 16; ++i) buf[i] = f4[(c + 1) * 1024 + i * 64 + l];
    }
    const float* fc = fch[c & 1];
    for (int tt = 0; tt < 256; ++tt) {
      int t = c * 256 + tt;
      int pb = t & 1;
      const float* vin = v_lds[pb];
      float m = vin[q * 4 + 0] + tr0; int mi = q * 4;
      float s1 = vin[q * 4 + 1] + tr1; if (s1 > m) { m = s1; mi = q * 4 + 1; }
      float s2 = vin[q * 4 + 2] + tr2; if (s2 > m) { m = s2; mi = q * 4 + 2; }
      float s3 = vin[q * 4 + 3] + tr3; if (s3 > m) { m = s3; mi = q * 4 + 3; }
      #pragma unroll
      for (int mask = 16; mask <= 32; mask <<= 1) {
        float om = __shfl_xor(m, mask);
        int omi = __shfl_xor(mi, mask);
        if (om > m || (om == m && omi < mi)) { m = om; mi = omi; }
      }
      int pmi = __shfl_xor(mi, 1);
      if (q == 0) {
        v_lds[pb ^ 1][next] = m + fc[tt * 16 + next];
        if ((next & 1) == 0)
          bp4[t * 8 + (next >> 1)] = (unsigned char)((mi & 15) | ((pmi & 15) << 4));
      }
      __syncthreads();   // one barrier per step (double-buffered v)
    }
    if (c < 7) {
      #pragma unroll
      for (int i = 0; i < 16; ++i) ((float4*)fch[(c + 1) & 1])[i * 64 + l] = buf[i];
      __syncthreads();
    }
  }

  // after t = S-1 (odd), final v is in v_lds[0]
  float term = (l < 16) ? (v_lds[0][l] + trans[1 * 16 + l]) : -3.0e38f;
  int ti = (l < 16) ? l : 0;
  #pragma unroll
  for (int mask = 1; mask <= 32; mask <<= 1) {
    float om = __shfl_xor(term, mask);
    int omi = __shfl_xor(ti, mask);
    if (om > term || (om == term && omi < ti)) { term = om; ti = omi; }
  }
  if (l == 0) {
    out[0] = term;
    int tag = ti;
    out[1 + (S - 1)] = (float)tag;
    for (int t = S - 1; t >= 1; --t) {
      tag = (bp4[t * 8 + (tag >> 1)] >> ((tag & 1) * 4)) & 15;
      out[t] = (float)tag;   // out[1 + (t-1)]
    }
  }
}

extern "C" void kernel_launch(void* const* d_in, const int* in_sizes, int n_in,
                              void* d_out, int out_size, void* d_ws, size_t ws_size,
                              hipStream_t stream) {
  const int*   sent  = (const int*)d_in[0];
  const float* emb   = (const float*)d_in[1];
  const float* Wih_f = (const float*)d_in[2];
  const float* Whh_f = (const float*)d_in[3];
  const float* bih_f = (const float*)d_in[4];
  const float* bhh_f = (const float*)d_in[5];
  const float* Wih_b = (const float*)d_in[6];
  const float* Whh_b = (const float*)d_in[7];
  const float* bih_b = (const float*)d_in[8];
  const float* bhh_b = (const float*)d_in[9];
  const float* h0    = (const float*)d_in[10];
  const float* c0    = (const float*)d_in[11];
  const float* Wout  = (const float*)d_in[12];
  const float* bout  = (const float*)d_in[13];
  const float* trans = (const float*)d_in[14];
  float* out = (float*)d_out;

  // workspace layout
  char* ws = (char*)d_ws;
  float* xg     = (float*)(ws);                         // 2048*4096*4 = 32 MiB
  float* hs_cat = (float*)(ws + 33554432);              // 2048*1024*4 = 8 MiB
  float* feats  = (float*)(ws + 41943040);              // 2048*16*4 = 128 KiB
  ull*   hbuf   = (ull*)  (ws + 42074112);              // 2*2*512*8 = 16 KiB

  init_h_k<<<2, 512, 0, stream>>>(h0, hbuf);
  gemm_xg_k<<<dim3(64, 32), 256, 0, stream>>>(sent, emb, Wih_f, Wih_b,
                                              bih_f, bhh_f, bih_b, bhh_b, xg);
  lstm_rec_k<<<128, 256, 0, stream>>>(Whh_f, Whh_b, c0, xg, hbuf, hs_cat);
  feats_k<<<2048, 64, 0, stream>>>(hs_cat, Wout, bout, feats);
  viterbi_k<<<1, 64, 0, stream>>>(feats, trans, out);
}

// Round 4
// 6663.616 us; speedup vs baseline: 1.5835x; 1.5835x over previous
//
#include <hip/hip_runtime.h>
#include <hip/hip_bf16.h>

#define S 2048
#define NEGV -10000.0f

typedef unsigned long long ull;

__device__ __forceinline__ float fsig(float x) {
  return 1.0f / (1.0f + __expf(-x));
}
__device__ __forceinline__ float ftanh(float x) {
  float a = fabsf(x);
  float e = __expf(-2.0f * a);
  float r = (1.0f - e) / (1.0f + e);
  return copysignf(r, x);
}

// ---------------- init: seed h0 with stamp 1, invalidate other slot ----------------
__global__ void init_h_k(const float* __restrict__ h0, ull* __restrict__ hbuf) {
  int dir = blockIdx.x;          // 0,1
  int u = threadIdx.x;           // 0..511
  ull pk = (1ULL << 32) | (ull)__float_as_uint(h0[dir * 512 + u]);
  __hip_atomic_store(&hbuf[dir * 1024 + u], pk, __ATOMIC_RELAXED, __HIP_MEMORY_SCOPE_AGENT);
  __hip_atomic_store(&hbuf[dir * 1024 + 512 + u], 0ULL, __ATOMIC_RELAXED, __HIP_MEMORY_SCOPE_AGENT);
}

// ---------------- xg GEMM: xg[m][n] = emb[sent[m]] . Wrow(n) + bias(n) ----------------
__global__ __launch_bounds__(256) void gemm_xg_k(
    const int* __restrict__ sent, const float* __restrict__ emb,
    const float* __restrict__ Wih_f, const float* __restrict__ Wih_b,
    const float* __restrict__ bih_f, const float* __restrict__ bhh_f,
    const float* __restrict__ bih_b, const float* __restrict__ bhh_b,
    float* __restrict__ xg)
{
  __shared__ __align__(16) float Asm[64 * 36];   // [64][36] pad
  __shared__ __align__(16) float Bsm[32 * 68];   // [32][68] pad, B[kk][n]
  __shared__ int sidx[64];

  const int bx = blockIdx.x;     // N tile 0..63
  const int by = blockIdx.y;     // M tile 0..31
  const int t = threadIdx.x;
  const int n0 = bx * 64, m0 = by * 64;

  const float* W = (n0 < 2048) ? (Wih_f + (size_t)n0 * 1024)
                               : (Wih_b + (size_t)(n0 - 2048) * 1024);
  if (t < 64) sidx[t] = sent[m0 + t];
  __syncthreads();

  const int tm = t >> 4, tn = t & 15;
  const int lr = t >> 2, lkq = t & 3;   // loader: row, k-quarter (8 floats)
  float acc[4][4] = {};

  for (int k0 = 0; k0 < 1024; k0 += 32) {
    const float* ap = emb + (size_t)sidx[lr] * 1024 + k0 + lkq * 8;
    float4 a0 = *(const float4*)ap;
    float4 a1 = *(const float4*)(ap + 4);
    const float* bp = W + (size_t)lr * 1024 + k0 + lkq * 8;
    float4 b0 = *(const float4*)bp;
    float4 b1 = *(const float4*)(bp + 4);
    __syncthreads();   // prior compute done before LDS overwrite
    *(float4*)&Asm[lr * 36 + lkq * 8]     = a0;
    *(float4*)&Asm[lr * 36 + lkq * 8 + 4] = a1;
    {
      const float* bb0 = (const float*)&b0;
      const float* bb1 = (const float*)&b1;
      #pragma unroll
      for (int j = 0; j < 4; ++j) Bsm[(lkq * 8 + j) * 68 + lr] = bb0[j];
      #pragma unroll
      for (int j = 0; j < 4; ++j) Bsm[(lkq * 8 + 4 + j) * 68 + lr] = bb1[j];
    }
    __syncthreads();
    #pragma unroll
    for (int kk = 0; kk < 32; ++kk) {
      float a0_ = Asm[(tm * 4 + 0) * 36 + kk];
      float a1_ = Asm[(tm * 4 + 1) * 36 + kk];
      float a2_ = Asm[(tm * 4 + 2) * 36 + kk];
      float a3_ = Asm[(tm * 4 + 3) * 36 + kk];
      float4 bv = *(const float4*)&Bsm[kk * 68 + tn * 4];
      acc[0][0] = fmaf(a0_, bv.x, acc[0][0]); acc[0][1] = fmaf(a0_, bv.y, acc[0][1]);
      acc[0][2] = fmaf(a0_, bv.z, acc[0][2]); acc[0][3] = fmaf(a0_, bv.w, acc[0][3]);
      acc[1][0] = fmaf(a1_, bv.x, acc[1][0]); acc[1][1] = fmaf(a1_, bv.y, acc[1][1]);
      acc[1][2] = fmaf(a1_, bv.z, acc[1][2]); acc[1][3] = fmaf(a1_, bv.w, acc[1][3]);
      acc[2][0] = fmaf(a2_, bv.x, acc[2][0]); acc[2][1] = fmaf(a2_, bv.y, acc[2][1]);
      acc[2][2] = fmaf(a2_, bv.z, acc[2][2]); acc[2][3] = fmaf(a2_, bv.w, acc[2][3]);
      acc[3][0] = fmaf(a3_, bv.x, acc[3][0]); acc[3][1] = fmaf(a3_, bv.y, acc[3][1]);
      acc[3][2] = fmaf(a3_, bv.z, acc[3][2]); acc[3][3] = fmaf(a3_, bv.w, acc[3][3]);
    }
  }

  const float* bi = (n0 < 2048) ? bih_f : bih_b;
  const float* bh = (n0 < 2048) ? bhh_f : bhh_b;
  const int nb = (n0 < 2048) ? n0 : (n0 - 2048);
  #pragma unroll
  for (int i = 0; i < 4; ++i) {
    int m = m0 + tm * 4 + i;
    #pragma unroll
    for (int j = 0; j < 4; ++j) {
      int nn = tn * 4 + j;
      float bias = bi[nb + nn] + bh[nb + nn];
      xg[(size_t)m * 4096 + n0 + nn] = acc[i][j] + bias;
    }
  }
}

// ---------------- persistent bidirectional LSTM recurrence ----------------
// 32 WGs x 1024 thr (1 CU each). dir = wg&1, wid = wg>>1 (0..15) owns units
// wid*32 .. wid*32+31 (128 gate rows). Weights stay in registers (64/thread).
// Exchange: 512 stamped (stamp<<32|f32) entries per direction, parity slots;
// only threads t<512 poll (1 entry each) -> 16 pollers per cache line per
// direction (vs 128 in r2) to kill LLC hot-line serialization. One intra-CU
// barrier per step; h staged in parity-double-buffered padded LDS.
__global__ __launch_bounds__(1024) void lstm_rec_k(
    const float* __restrict__ Whh_f, const float* __restrict__ Whh_b,
    const float* __restrict__ c0,
    const float* __restrict__ xg,      // [S][4096]
    ull* __restrict__ hbuf,            // [2 dir][2 slot][512]
    float* __restrict__ hs_cat)        // [S][1024]
{
  const int w = blockIdx.x;
  const int dir = w & 1;
  const int wid = w >> 1;              // 0..15
  const int t = threadIdx.x;           // 0..1023
  const int wv = t >> 6;               // wave 0..15
  const int l  = t & 63;               // lane
  const int rr = l >> 3;               // row-in-wave 0..7
  const int seg = l & 7;               // 0..7
  const int g  = rr & 3;               // gate 0..3 (i,f,g,o)
  const int ulg = wv * 2 + (rr >> 2);  // local unit 0..31
  const int unit = wid * 32 + ulg;     // 0..511
  const int grow = g * 512 + unit;     // global gate row (0..2047)

  const float* Whh = dir ? Whh_b : Whh_f;

  float wreg[64];
  {
    const float* src = Whh + (size_t)grow * 512 + seg * 64;
    #pragma unroll
    for (int j = 0; j < 16; ++j) {
      float4 v = *(const float4*)(src + j * 4);
      wreg[4 * j + 0] = v.x; wreg[4 * j + 1] = v.y;
      wreg[4 * j + 2] = v.z; wreg[4 * j + 3] = v.w;
    }
  }

  // parity-double-buffered staging: 8 chunks * 68-float stride (bank-spread)
  __shared__ __align__(16) float h_lds[2][544];

  ull* hb = hbuf + dir * 1024;

  float c_reg = c0[dir * 512 + unit];  // meaningful on g==0 lanes

  // xg 2-step software pipeline
  float xg_cur = 0.0f, xg_next = 0.0f;
  if (seg == 0) {
    int rowk = dir ? (S - 1) : 0;
    xg_cur = xg[(size_t)rowk * 4096 + dir * 2048 + grow];
  }

  for (int k = 0; k < S; ++k) {
    if (seg == 0 && k + 1 < S) {
      int rowk = dir ? (S - 2 - k) : (k + 1);
      xg_next = xg[(size_t)rowk * 4096 + dir * 2048 + grow];
    }
    // poll h_k: stamp k+1 in slot k&1 (threads 0..511, 1 entry each)
    if (t < 512) {
      ull* src = hb + (k & 1) * 512 + t;
      const unsigned want = (unsigned)(k + 1);
      ull v = __hip_atomic_load(src, __ATOMIC_RELAXED, __HIP_MEMORY_SCOPE_AGENT);
      while ((unsigned)(v >> 32) != want)
        v = __hip_atomic_load(src, __ATOMIC_RELAXED, __HIP_MEMORY_SCOPE_AGENT);
      h_lds[k & 1][(t >> 6) * 68 + (t & 63)] = __uint_as_float((unsigned)v);
    }
    __syncthreads();   // single intra-CU barrier per step

    // partial dot: this thread's 64-wide segment of row `grow`
    const float* hw = h_lds[k & 1];
    float p0 = 0.f, p1 = 0.f, p2 = 0.f, p3 = 0.f;
    const float4* h4 = (const float4*)(hw + seg * 68);
    #pragma unroll
    for (int j = 0; j < 16; ++j) {
      float4 hv = h4[j];
      p0 = fmaf(wreg[4 * j + 0], hv.x, p0);
      p1 = fmaf(wreg[4 * j + 1], hv.y, p1);
      p2 = fmaf(wreg[4 * j + 2], hv.z, p2);
      p3 = fmaf(wreg[4 * j + 3], hv.w, p3);
    }
    float p = (p0 + p1) + (p2 + p3) + xg_cur;   // xg_cur nonzero only on seg==0
    // butterfly within 8-lane segment group -> all 8 lanes hold the row sum
    p += __shfl_xor(p, 1);
    p += __shfl_xor(p, 2);
    p += __shfl_xor(p, 4);
    // gather the 4 gates of this unit (rows 8 lanes apart) in-register
    float gb_ = __shfl_xor(p, 8);     // gate g^1
    float gc_ = __shfl_xor(p, 16);    // gate g^2
    float gd_ = __shfl_xor(gb_, 16);  // gate g^3
    if (g == 0) {
      float iv = fsig(p), fv = fsig(gb_), ov = fsig(gd_);
      float gv = ftanh(gc_);
      c_reg = fv * c_reg + iv * gv;
      float hv = ov * ftanh(c_reg);
      if (seg == 0) {
        // publish FIRST (critical path), then archive to hs_cat
        ull pk = ((ull)(unsigned)(k + 2) << 32) | (ull)__float_as_uint(hv);
        __hip_atomic_store(&hb[((k + 1) & 1) * 512 + unit], pk,
                           __ATOMIC_RELAXED, __HIP_MEMORY_SCOPE_AGENT);
        int orig = dir ? (S - 1 - k) : k;
        hs_cat[(size_t)orig * 1024 + dir * 512 + unit] = hv;
      }
    }
    xg_cur = xg_next;
  }
}

// ---------------- feats[t][j] = hs_cat[t] . Wout[j] + bout[j] ----------------
__global__ __launch_bounds__(64) void feats_k(
    const float* __restrict__ hs_cat, const float* __restrict__ Wout,
    const float* __restrict__ bout, float* __restrict__ feats)
{
  int tpos = blockIdx.x;
  int l = threadIdx.x;
  int j = l & 15, q = l >> 4;
  const float* h = hs_cat + (size_t)tpos * 1024 + q * 256;
  const float* wv = Wout + (size_t)j * 1024 + q * 256;
  float s = 0.f;
  #pragma unroll 8
  for (int i = 0; i < 256; i += 4) {
    float4 hv = *(const float4*)(h + i);
    float4 ww = *(const float4*)(wv + i);
    s = fmaf(hv.x, ww.x, s); s = fmaf(hv.y, ww.y, s);
    s = fmaf(hv.z, ww.z, s); s = fmaf(hv.w, ww.w, s);
  }
  s += __shfl_xor(s, 16);
  s += __shfl_xor(s, 32);
  if (q == 0) feats[tpos * 16 + j] = s + bout[j];
}

// ---------------- Viterbi: single wave, LDS-chunked feats, 4-bit backpointers ----------------
__global__ __launch_bounds__(64, 1) void viterbi_k(
    const float* __restrict__ feats, const float* __restrict__ trans,
    float* __restrict__ out)
{
  __shared__ __align__(16) float fch[2][256 * 16];  // 2 x 16KB double-buffer
  __shared__ unsigned char bp4[S * 8];              // 16KB packed nibbles
  __shared__ float v_lds[2][16];                    // double-buffered by step parity

  const int l = threadIdx.x;
  const int next = l & 15, q = l >> 4;

  float tr0 = trans[next * 16 + q * 4 + 0];
  float tr1 = trans[next * 16 + q * 4 + 1];
  float tr2 = trans[next * 16 + q * 4 + 2];
  float tr3 = trans[next * 16 + q * 4 + 3];

  if (l < 16) v_lds[0][l] = (l == 0) ? 0.0f : NEGV;   // START = 0

  const float4* f4 = (const float4*)feats;
  float4 buf[16];
  #pragma unroll
  for (int i = 0; i < 16; ++i) buf[i] = f4[i * 64 + l];
  #pragma unroll
  for (int i = 0; i < 16; ++i) ((float4*)fch[0])[i * 64 + l] = buf[i];
  __syncthreads();

  for (int c = 0; c < 8; ++c) {
    if (c < 7) {
      #pragma unroll
      for (int i = 0; i < 16; ++i) buf[i] = f4[(c + 1) * 1024 + i * 64 + l];
    }
    const float* fc = fch[c & 1];
    for (int tt = 0; tt < 256; ++tt) {
      int t = c * 256 + tt;
      int pb = t & 1;
      const float* vin = v_lds[pb];
      float m = vin[q * 4 + 0] + tr0; int mi = q * 4;
      float s1 = vin[q * 4 + 1] + tr1; if (s1 > m) { m = s1; mi = q * 4 + 1; }
      float s2 = vin[q * 4 + 2] + tr2; if (s2 > m) { m = s2; mi = q * 4 + 2; }
      float s3 = vin[q * 4 + 3] + tr3; if (s3 > m) { m = s3; mi = q * 4 + 3; }
      #pragma unroll
      for (int mask = 16; mask <= 32; mask <<= 1) {
        float om = __shfl_xor(m, mask);
        int omi = __shfl_xor(mi, mask);
        if (om > m || (om == m && omi < mi)) { m = om; mi = omi; }
      }
      int pmi = __shfl_xor(mi, 1);
      if (q == 0) {
        v_lds[pb ^ 1][next] = m + fc[tt * 16 + next];
        if ((next & 1) == 0)
          bp4[t * 8 + (next >> 1)] = (unsigned char)((mi & 15) | ((pmi & 15) << 4));
      }
      __syncthreads();   // one barrier per step (double-buffered v)
    }
    if (c < 7) {
      #pragma unroll
      for (int i = 0; i < 16; ++i) ((float4*)fch[(c + 1) & 1])[i * 64 + l] = buf[i];
      __syncthreads();
    }
  }

  // after t = S-1 (odd), final v is in v_lds[0]
  float term = (l < 16) ? (v_lds[0][l] + trans[1 * 16 + l]) : -3.0e38f;
  int ti = (l < 16) ? l : 0;
  #pragma unroll
  for (int mask = 1; mask <= 32; mask <<= 1) {
    float om = __shfl_xor(term, mask);
    int omi = __shfl_xor(ti, mask);
    if (om > term || (om == term && omi < ti)) { term = om; ti = omi; }
  }
  if (l == 0) {
    out[0] = term;
    int tag = ti;
    out[1 + (S - 1)] = (float)tag;
    for (int t = S - 1; t >= 1; --t) {
      tag = (bp4[t * 8 + (tag >> 1)] >> ((tag & 1) * 4)) & 15;
      out[t] = (float)tag;   // out[1 + (t-1)]
    }
  }
}

extern "C" void kernel_launch(void* const* d_in, const int* in_sizes, int n_in,
                              void* d_out, int out_size, void* d_ws, size_t ws_size,
                              hipStream_t stream) {
  const int*   sent  = (const int*)d_in[0];
  const float* emb   = (const float*)d_in[1];
  const float* Wih_f = (const float*)d_in[2];
  const float* Whh_f = (const float*)d_in[3];
  const float* bih_f = (const float*)d_in[4];
  const float* bhh_f = (const float*)d_in[5];
  const float* Wih_b = (const float*)d_in[6];
  const float* Whh_b = (const float*)d_in[7];
  const float* bih_b = (const float*)d_in[8];
  const float* bhh_b = (const float*)d_in[9];
  const float* h0    = (const float*)d_in[10];
  const float* c0    = (const float*)d_in[11];
  const float* Wout  = (const float*)d_in[12];
  const float* bout  = (const float*)d_in[13];
  const float* trans = (const float*)d_in[14];
  float* out = (float*)d_out;

  // workspace layout
  char* ws = (char*)d_ws;
  float* xg     = (float*)(ws);                         // 2048*4096*4 = 32 MiB
  float* hs_cat = (float*)(ws + 33554432);              // 2048*1024*4 = 8 MiB
  float* feats  = (float*)(ws + 41943040);              // 2048*16*4 = 128 KiB
  ull*   hbuf   = (ull*)  (ws + 42074112);              // 2*2*512*8 = 16 KiB

  init_h_k<<<2, 512, 0, stream>>>(h0, hbuf);
  gemm_xg_k<<<dim3(64, 32), 256, 0, stream>>>(sent, emb, Wih_f, Wih_b,
                                              bih_f, bhh_f, bih_b, bhh_b, xg);
  lstm_rec_k<<<32, 1024, 0, stream>>>(Whh_f, Whh_b, c0, xg, hbuf, hs_cat);
  feats_k<<<2048, 64, 0, stream>>>(hs_cat, Wout, bout, feats);
  viterbi_k<<<1, 64, 0, stream>>>(feats, trans, out);
}

// Round 5
// 4034.168 us; speedup vs baseline: 2.6156x; 1.6518x over previous
//
#include <hip/hip_runtime.h>
#include <hip/hip_bf16.h>

#define S 2048
#define NEGV -10000.0f

typedef unsigned long long ull;
typedef unsigned int uint4v __attribute__((ext_vector_type(4)));

__device__ __forceinline__ float fsig(float x) {
  return 1.0f / (1.0f + __expf(-x));
}
__device__ __forceinline__ float ftanh(float x) {
  float a = fabsf(x);
  float e = __expf(-2.0f * a);
  float r = (1.0f - e) / (1.0f + e);
  return copysignf(r, x);
}

// ---------------- init: seed h0 with stamp 1, invalidate other slot ----------------
__global__ void init_h_k(const float* __restrict__ h0, ull* __restrict__ hbuf) {
  int dir = blockIdx.x;          // 0,1
  int u = threadIdx.x;           // 0..511
  ull pk = (1ULL << 32) | (ull)__float_as_uint(h0[dir * 512 + u]);
  __hip_atomic_store(&hbuf[dir * 1024 + u], pk, __ATOMIC_RELAXED, __HIP_MEMORY_SCOPE_AGENT);
  __hip_atomic_store(&hbuf[dir * 1024 + 512 + u], 0ULL, __ATOMIC_RELAXED, __HIP_MEMORY_SCOPE_AGENT);
}

// ---------------- xg GEMM: xg[m][n] = emb[sent[m]] . Wrow(n) + bias(n) ----------------
__global__ __launch_bounds__(256) void gemm_xg_k(
    const int* __restrict__ sent, const float* __restrict__ emb,
    const float* __restrict__ Wih_f, const float* __restrict__ Wih_b,
    const float* __restrict__ bih_f, const float* __restrict__ bhh_f,
    const float* __restrict__ bih_b, const float* __restrict__ bhh_b,
    float* __restrict__ xg)
{
  __shared__ __align__(16) float Asm[64 * 36];   // [64][36] pad
  __shared__ __align__(16) float Bsm[32 * 68];   // [32][68] pad, B[kk][n]
  __shared__ int sidx[64];

  const int bx = blockIdx.x;     // N tile 0..63
  const int by = blockIdx.y;     // M tile 0..31
  const int t = threadIdx.x;
  const int n0 = bx * 64, m0 = by * 64;

  const float* W = (n0 < 2048) ? (Wih_f + (size_t)n0 * 1024)
                               : (Wih_b + (size_t)(n0 - 2048) * 1024);
  if (t < 64) sidx[t] = sent[m0 + t];
  __syncthreads();

  const int tm = t >> 4, tn = t & 15;
  const int lr = t >> 2, lkq = t & 3;   // loader: row, k-quarter (8 floats)
  float acc[4][4] = {};

  for (int k0 = 0; k0 < 1024; k0 += 32) {
    const float* ap = emb + (size_t)sidx[lr] * 1024 + k0 + lkq * 8;
    float4 a0 = *(const float4*)ap;
    float4 a1 = *(const float4*)(ap + 4);
    const float* bp = W + (size_t)lr * 1024 + k0 + lkq * 8;
    float4 b0 = *(const float4*)bp;
    float4 b1 = *(const float4*)(bp + 4);
    __syncthreads();   // prior compute done before LDS overwrite
    *(float4*)&Asm[lr * 36 + lkq * 8]     = a0;
    *(float4*)&Asm[lr * 36 + lkq * 8 + 4] = a1;
    {
      const float* bb0 = (const float*)&b0;
      const float* bb1 = (const float*)&b1;
      #pragma unroll
      for (int j = 0; j < 4; ++j) Bsm[(lkq * 8 + j) * 68 + lr] = bb0[j];
      #pragma unroll
      for (int j = 0; j < 4; ++j) Bsm[(lkq * 8 + 4 + j) * 68 + lr] = bb1[j];
    }
    __syncthreads();
    #pragma unroll
    for (int kk = 0; kk < 32; ++kk) {
      float a0_ = Asm[(tm * 4 + 0) * 36 + kk];
      float a1_ = Asm[(tm * 4 + 1) * 36 + kk];
      float a2_ = Asm[(tm * 4 + 2) * 36 + kk];
      float a3_ = Asm[(tm * 4 + 3) * 36 + kk];
      float4 bv = *(const float4*)&Bsm[kk * 68 + tn * 4];
      acc[0][0] = fmaf(a0_, bv.x, acc[0][0]); acc[0][1] = fmaf(a0_, bv.y, acc[0][1]);
      acc[0][2] = fmaf(a0_, bv.z, acc[0][2]); acc[0][3] = fmaf(a0_, bv.w, acc[0][3]);
      acc[1][0] = fmaf(a1_, bv.x, acc[1][0]); acc[1][1] = fmaf(a1_, bv.y, acc[1][1]);
      acc[1][2] = fmaf(a1_, bv.z, acc[1][2]); acc[1][3] = fmaf(a1_, bv.w, acc[1][3]);
      acc[2][0] = fmaf(a2_, bv.x, acc[2][0]); acc[2][1] = fmaf(a2_, bv.y, acc[2][1]);
      acc[2][2] = fmaf(a2_, bv.z, acc[2][2]); acc[2][3] = fmaf(a2_, bv.w, acc[2][3]);
      acc[3][0] = fmaf(a3_, bv.x, acc[3][0]); acc[3][1] = fmaf(a3_, bv.y, acc[3][1]);
      acc[3][2] = fmaf(a3_, bv.z, acc[3][2]); acc[3][3] = fmaf(a3_, bv.w, acc[3][3]);
    }
  }

  const float* bi = (n0 < 2048) ? bih_f : bih_b;
  const float* bh = (n0 < 2048) ? bhh_f : bhh_b;
  const int nb = (n0 < 2048) ? n0 : (n0 - 2048);
  #pragma unroll
  for (int i = 0; i < 4; ++i) {
    int m = m0 + tm * 4 + i;
    #pragma unroll
    for (int j = 0; j < 4; ++j) {
      int nn = tn * 4 + j;
      float bias = bi[nb + nn] + bh[nb + nn];
      xg[(size_t)m * 4096 + n0 + nn] = acc[i][j] + bias;
    }
  }
}

// ---------------- persistent bidirectional LSTM recurrence ----------------
// R2 topology: 128 WGs x 256 thr. dir = wg&1, wid = wg>>1 owns units wid*8..+7.
// This round: (1) poll via 16B global_load_dwordx4 sc0/sc1 (2 stamped entries
// per request, coalescable, tearing only at the 8B atomic granularity -> safe);
// (2) s_sleep(2) backoff between retry rounds; (3) 2x-unrolled step loop with
// disjoint xg registers (no reg-copy -> no stray vmcnt serialization);
// (4) publish-first ordering.
__global__ __launch_bounds__(256, 1) void lstm_rec_k(
    const float* __restrict__ Whh_f, const float* __restrict__ Whh_b,
    const float* __restrict__ c0,
    const float* __restrict__ xg,      // [S][4096]
    ull* __restrict__ hbuf,            // [2 dir][2 slot][512]
    float* __restrict__ hs_cat)        // [S][1024]
{
  const int w = blockIdx.x;
  const int dir = w & 1;
  const int wid = w >> 1;              // 0..63
  const int t = threadIdx.x;
  const int rr = t >> 3;               // row-in-wg 0..31
  const int seg = t & 7;               // 0..7
  const int g  = rr & 3;               // gate 0..3 (i,f,g,o)
  const int ul = rr >> 2;              // local unit 0..7
  const int unit = wid * 8 + ul;       // 0..511
  const int grow = g * 512 + unit;     // global Whh row

  const float* Whh = dir ? Whh_b : Whh_f;

  float wreg[64];
  {
    const float* src = Whh + (size_t)grow * 512 + seg * 64;
    #pragma unroll
    for (int j = 0; j < 16; ++j) {
      float4 v = *(const float4*)(src + j * 4);
      wreg[4 * j + 0] = v.x; wreg[4 * j + 1] = v.y;
      wreg[4 * j + 2] = v.z; wreg[4 * j + 3] = v.w;
    }
  }

  // [parity][8 chunks * 68 floats] padded staging (bank-spread, conflict-free)
  __shared__ __align__(16) float h_lds[2][544];

  ull* hb = hbuf + dir * 1024;

  float c_reg = c0[dir * 512 + unit];  // meaningful on g==0 lanes

  const int u0 = t * 2;
  const int wchunk = u0 >> 6;          // LDS chunk for this thread's pair
  const int wpos   = u0 & 63;

  // xg pipeline: xg_a feeds even steps, xg_b odd steps (seg==0 lanes only)
  float xg_a = 0.0f, xg_b = 0.0f;
  if (seg == 0) {
    int r0 = dir ? (S - 1) : 0;
    int r1 = dir ? (S - 2) : 1;
    xg_a = xg[(size_t)r0 * 4096 + dir * 2048 + grow];
    xg_b = xg[(size_t)r1 * 4096 + dir * 2048 + grow];
  }

  #define LSTM_STEP(K, XG_REG)                                                  \
  {                                                                             \
    const int k = (K);                                                          \
    float xgv = XG_REG;                                                         \
    if (seg == 0 && k + 2 < S) {       /* prefetch k+2 into same reg */         \
      int rowk = dir ? (S - 3 - k) : (k + 2);                                   \
      XG_REG = xg[(size_t)rowk * 4096 + dir * 2048 + grow];                     \
    }                                                                           \
    /* poll h_k: stamp k+1 in slot k&1; 16B coherent load, sleep backoff */     \
    {                                                                           \
      ull* src = hb + (k & 1) * 512 + u0;                                       \
      const unsigned want = (unsigned)(k + 1);                                  \
      uint4v v;                                                                 \
      asm volatile("global_load_dwordx4 %0, %1, off sc0 sc1"                    \
                   : "=v"(v) : "v"(src) : "memory");                            \
      asm volatile("s_waitcnt vmcnt(0)" ::: "memory");                          \
      while (v.y != want || v.w != want) {                                      \
        __builtin_amdgcn_s_sleep(2);                                            \
        asm volatile("global_load_dwordx4 %0, %1, off sc0 sc1"                  \
                     : "=v"(v) : "v"(src) : "memory");                          \
        asm volatile("s_waitcnt vmcnt(0)" ::: "memory");                        \
      }                                                                         \
      float* dst = &h_lds[k & 1][wchunk * 68 + wpos];                           \
      dst[0] = __uint_as_float(v.x);                                            \
      dst[1] = __uint_as_float(v.z);                                            \
    }                                                                           \
    __syncthreads();                                                            \
    /* 64-wide partial dot of row `grow` */                                     \
    const float* hl = &h_lds[k & 1][0];                                         \
    float p0 = 0.f, p1 = 0.f, p2 = 0.f, p3 = 0.f;                               \
    const float4* h4 = (const float4*)(hl + seg * 68);                          \
    _Pragma("unroll")                                                           \
    for (int j = 0; j < 16; ++j) {                                              \
      float4 hv = h4[j];                                                        \
      p0 = fmaf(wreg[4 * j + 0], hv.x, p0);                                     \
      p1 = fmaf(wreg[4 * j + 1], hv.y, p1);                                     \
      p2 = fmaf(wreg[4 * j + 2], hv.z, p2);                                     \
      p3 = fmaf(wreg[4 * j + 3], hv.w, p3);                                     \
    }                                                                           \
    float p = (p0 + p1) + (p2 + p3) + xgv;                                      \
    p += __shfl_xor(p, 1);                                                      \
    p += __shfl_xor(p, 2);                                                      \
    p += __shfl_xor(p, 4);                                                      \
    float gb_ = __shfl_xor(p, 8);      /* gate g^1 */                           \
    float gc_ = __shfl_xor(p, 16);     /* gate g^2 */                           \
    float gd_ = __shfl_xor(gb_, 16);   /* gate g^3 */                           \
    if (g == 0) {                                                               \
      float iv = fsig(p), fv = fsig(gb_), ov = fsig(gd_);                       \
      float gv = ftanh(gc_);                                                    \
      c_reg = fv * c_reg + iv * gv;                                             \
      float hv = ov * ftanh(c_reg);                                             \
      if (seg == 0) {                                                           \
        ull pk = ((ull)(unsigned)(k + 2) << 32) | (ull)__float_as_uint(hv);     \
        __hip_atomic_store(&hb[((k + 1) & 1) * 512 + unit], pk,                 \
                           __ATOMIC_RELAXED, __HIP_MEMORY_SCOPE_AGENT);         \
        int orig = dir ? (S - 1 - k) : k;                                       \
        hs_cat[(size_t)orig * 1024 + dir * 512 + unit] = hv;                    \
      }                                                                         \
    }                                                                           \
  }

  for (int kk = 0; kk < S; kk += 2) {
    LSTM_STEP(kk, xg_a);
    LSTM_STEP(kk + 1, xg_b);
  }
  #undef LSTM_STEP
}

// ---------------- feats[t][j] = hs_cat[t] . Wout[j] + bout[j] ----------------
__global__ __launch_bounds__(64) void feats_k(
    const float* __restrict__ hs_cat, const float* __restrict__ Wout,
    const float* __restrict__ bout, float* __restrict__ feats)
{
  int tpos = blockIdx.x;
  int l = threadIdx.x;
  int j = l & 15, q = l >> 4;
  const float* h = hs_cat + (size_t)tpos * 1024 + q * 256;
  const float* wv = Wout + (size_t)j * 1024 + q * 256;
  float s = 0.f;
  #pragma unroll 8
  for (int i = 0; i < 256; i += 4) {
    float4 hv = *(const float4*)(h + i);
    float4 ww = *(const float4*)(wv + i);
    s = fmaf(hv.x, ww.x, s); s = fmaf(hv.y, ww.y, s);
    s = fmaf(hv.z, ww.z, s); s = fmaf(hv.w, ww.w, s);
  }
  s += __shfl_xor(s, 16);
  s += __shfl_xor(s, 32);
  if (q == 0) feats[tpos * 16 + j] = s + bout[j];
}

// ---------------- Viterbi: single wave, LDS-chunked feats, 4-bit backpointers ----------------
__global__ __launch_bounds__(64, 1) void viterbi_k(
    const float* __restrict__ feats, const float* __restrict__ trans,
    float* __restrict__ out)
{
  __shared__ __align__(16) float fch[2][256 * 16];  // 2 x 16KB double-buffer
  __shared__ unsigned char bp4[S * 8];              // 16KB packed nibbles
  __shared__ float v_lds[2][16];                    // double-buffered by step parity

  const int l = threadIdx.x;
  const int next = l & 15, q = l >> 4;

  float tr0 = trans[next * 16 + q * 4 + 0];
  float tr1 = trans[next * 16 + q * 4 + 1];
  float tr2 = trans[next * 16 + q * 4 + 2];
  float tr3 = trans[next * 16 + q * 4 + 3];

  if (l < 16) v_lds[0][l] = (l == 0) ? 0.0f : NEGV;   // START = 0

  const float4* f4 = (const float4*)feats;
  float4 buf[16];
  #pragma unroll
  for (int i = 0; i < 16; ++i) buf[i] = f4[i * 64 + l];
  #pragma unroll
  for (int i = 0; i < 16; ++i) ((float4*)fch[0])[i * 64 + l] = buf[i];
  __syncthreads();

  for (int c = 0; c < 8; ++c) {
    if (c < 7) {
      #pragma unroll
      for (int i = 0; i < 16; ++i) buf[i] = f4[(c + 1) * 1024 + i * 64 + l];
    }
    const float* fc = fch[c & 1];
    for (int tt = 0; tt < 256; ++tt) {
      int t = c * 256 + tt;
      int pb = t & 1;
      const float* vin = v_lds[pb];
      float m = vin[q * 4 + 0] + tr0; int mi = q * 4;
      float s1 = vin[q * 4 + 1] + tr1; if (s1 > m) { m = s1; mi = q * 4 + 1; }
      float s2 = vin[q * 4 + 2] + tr2; if (s2 > m) { m = s2; mi = q * 4 + 2; }
      float s3 = vin[q * 4 + 3] + tr3; if (s3 > m) { m = s3; mi = q * 4 + 3; }
      #pragma unroll
      for (int mask = 16; mask <= 32; mask <<= 1) {
        float om = __shfl_xor(m, mask);
        int omi = __shfl_xor(mi, mask);
        if (om > m || (om == m && omi < mi)) { m = om; mi = omi; }
      }
      int pmi = __shfl_xor(mi, 1);
      if (q == 0) {
        v_lds[pb ^ 1][next] = m + fc[tt * 16 + next];
        if ((next & 1) == 0)
          bp4[t * 8 + (next >> 1)] = (unsigned char)((mi & 15) | ((pmi & 15) << 4));
      }
      __syncthreads();   // one barrier per step (double-buffered v)
    }
    if (c < 7) {
      #pragma unroll
      for (int i = 0; i < 16; ++i) ((float4*)fch[(c + 1) & 1])[i * 64 + l] = buf[i];
      __syncthreads();
    }
  }

  // after t = S-1 (odd), final v is in v_lds[0]
  float term = (l < 16) ? (v_lds[0][l] + trans[1 * 16 + l]) : -3.0e38f;
  int ti = (l < 16) ? l : 0;
  #pragma unroll
  for (int mask = 1; mask <= 32; mask <<= 1) {
    float om = __shfl_xor(term, mask);
    int omi = __shfl_xor(ti, mask);
    if (om > term || (om == term && omi < ti)) { term = om; ti = omi; }
  }
  if (l == 0) {
    out[0] = term;
    int tag = ti;
    out[1 + (S - 1)] = (float)tag;
    for (int t = S - 1; t >= 1; --t) {
      tag = (bp4[t * 8 + (tag >> 1)] >> ((tag & 1) * 4)) & 15;
      out[t] = (float)tag;   // out[1 + (t-1)]
    }
  }
}

extern "C" void kernel_launch(void* const* d_in, const int* in_sizes, int n_in,
                              void* d_out, int out_size, void* d_ws, size_t ws_size,
                              hipStream_t stream) {
  const int*   sent  = (const int*)d_in[0];
  const float* emb   = (const float*)d_in[1];
  const float* Wih_f = (const float*)d_in[2];
  const float* Whh_f = (const float*)d_in[3];
  const float* bih_f = (const float*)d_in[4];
  const float* bhh_f = (const float*)d_in[5];
  const float* Wih_b = (const float*)d_in[6];
  const float* Whh_b = (const float*)d_in[7];
  const float* bih_b = (const float*)d_in[8];
  const float* bhh_b = (const float*)d_in[9];
  const float* h0    = (const float*)d_in[10];
  const float* c0    = (const float*)d_in[11];
  const float* Wout  = (const float*)d_in[12];
  const float* bout  = (const float*)d_in[13];
  const float* trans = (const float*)d_in[14];
  float* out = (float*)d_out;

  // workspace layout
  char* ws = (char*)d_ws;
  float* xg     = (float*)(ws);                         // 2048*4096*4 = 32 MiB
  float* hs_cat = (float*)(ws + 33554432);              // 2048*1024*4 = 8 MiB
  float* feats  = (float*)(ws + 41943040);              // 2048*16*4 = 128 KiB
  ull*   hbuf   = (ull*)  (ws + 42074112);              // 2*2*512*8 = 16 KiB

  init_h_k<<<2, 512, 0, stream>>>(h0, hbuf);
  gemm_xg_k<<<dim3(64, 32), 256, 0, stream>>>(sent, emb, Wih_f, Wih_b,
                                              bih_f, bhh_f, bih_b, bhh_b, xg);
  lstm_rec_k<<<128, 256, 0, stream>>>(Whh_f, Whh_b, c0, xg, hbuf, hs_cat);
  feats_k<<<2048, 64, 0, stream>>>(hs_cat, Wout, bout, feats);
  viterbi_k<<<1, 64, 0, stream>>>(feats, trans, out);
}